// Round 2
// baseline (253.430 us; speedup 1.0000x reference)
//
#include <hip/hip_runtime.h>
#include <math.h>
#include <stdint.h>

#define VOCAB 100000
#define DIM   128
#define BATCH 16384
#define CMAX  10
#define KNEG  5
#define RMAX  (CMAX + KNEG)   // 15 score slots max

typedef float f32x2 __attribute__((ext_vector_type(2)));

// Numerically stable log(sigmoid(x)) = min(x,0) - log1p(exp(-|x|))
__device__ __forceinline__ float log_sigmoid(float x) {
    return fminf(x, 0.0f) - log1pf(expf(-fabsf(x)));
}

#define DPP_ADD_STEP(v, ctrl)                                                  \
    v += __int_as_float(__builtin_amdgcn_update_dpp(                           \
        0, __float_as_int(v), (ctrl), 0xF, 0xF, false))

// Full 64-lane sum; total lands on lane 63.
__device__ __forceinline__ float dpp_reduce64_to_lane63(float v) {
    DPP_ADD_STEP(v, 0x111);  // row_shr:1
    DPP_ADD_STEP(v, 0x112);  // row_shr:2
    DPP_ADD_STEP(v, 0x114);  // row_shr:4
    DPP_ADD_STEP(v, 0x118);  // row_shr:8
    DPP_ADD_STEP(v, 0x142);  // row_bcast:15
    DPP_ADD_STEP(v, 0x143);  // row_bcast:31
    return v;
}

// ---------------------------------------------------------------------------
// One wave per sample. Each embedding row is fetched by ONE
// global_load_dwordx2 (64 lanes x 8 B = exactly one 512 B row, single
// coalesced segment). Only len+KNEG rows are fetched (len is wave-uniform,
// so the variable trip count is a uniform branch): rows with j >= len were
// previously gathered and masked to zero -- mean len is 5, so this cuts
// gather traffic ~40% (147 MB -> ~88 MB). t-row fetched exactly once per
// sample. len==0 waves fetch nothing (reference skips them entirely).
// Loss fused as before; per_sample gets (pos_per, neg_per).
// ---------------------------------------------------------------------------
__global__ __launch_bounds__(256) void score_loss_kernel(
    const int*   __restrict__ tgt,
    const int*   __restrict__ ctx,
    const int*   __restrict__ lens,
    const int*   __restrict__ neg,
    const float* __restrict__ in_emb,
    const float* __restrict__ out_emb,
    float2*      __restrict__ per_sample,  // ws: [BATCH]
    float*       __restrict__ out)
{
    const int tid  = threadIdx.x;
    const int lane = tid & 63;
    const int b    = (blockIdx.x * 256 + tid) >> 6;   // one wave per sample

    if (blockIdx.x == 0 && tid < 2) out[tid] = 0.0f;

    const int len = lens[b];                          // wave-uniform
    float2 res; res.x = 0.0f; res.y = 0.0f;

    if (len > 0) {                                    // uniform branch
        const int R      = len + KNEG;                // 6..15 live slots
        const int t_word = tgt[b];

        // slot j: j<len -> ctx word j ; len<=j<R -> neg word j-len.
        // Indices clamped so a compiler-speculated wrong-arm load stays
        // in bounds.
        int words[RMAX];
#pragma unroll
        for (int j = 0; j < RMAX; ++j) {
            if (j < R) {
                const int cj = (j < CMAX) ? j : (CMAX - 1);
                int nj = j - len;
                nj = (nj < 0) ? 0 : ((nj > KNEG - 1) ? (KNEG - 1) : nj);
                words[j] = (j < len) ? ctx[b * CMAX + cj]
                                     : neg[b * KNEG + nj];
            }
        }

        // ---- issue 1 + R row loads back-to-back, one row per instr ----
        const uint32_t lane8 = (uint32_t)lane * 8u;
        f32x2 tv;
        asm volatile("global_load_dwordx2 %0, %1, %2"
                     : "=v"(tv)
                     : "v"((uint32_t)t_word * (DIM * 4u) + lane8),
                       "s"(in_emb));
        f32x2 rv[RMAX];
#pragma unroll
        for (int j = 0; j < RMAX; ++j) {
            if (j < R) {
                asm volatile("global_load_dwordx2 %0, %1, %2"
                             : "=v"(rv[j])
                             : "v"((uint32_t)words[j] * (DIM * 4u) + lane8),
                               "s"(out_emb));
            }
        }
        asm volatile("s_waitcnt vmcnt(0)" ::: "memory");
        __builtin_amdgcn_sched_barrier(0);   // rule #18: pin consumers below

        // ---- per-row dot + full-wave reduce; broadcast result ----
        float bc[RMAX];
#pragma unroll
        for (int j = 0; j < RMAX; ++j) bc[j] = 0.0f;
#pragma unroll
        for (int j = 0; j < RMAX; ++j) {
            if (j < R) {
                float d = tv.x * rv[j].x + tv.y * rv[j].y;
                float s = dpp_reduce64_to_lane63(d);
                bc[j] = __shfl(s, 63, 64);
            }
        }

        // ---- 16-way mux: lane sel picks bc[sel] (slot 15 := 0) ----
        const int sel = lane & 15;
        float m0 = (sel & 1) ? bc[1]  : bc[0];
        float m1 = (sel & 1) ? bc[3]  : bc[2];
        float m2 = (sel & 1) ? bc[5]  : bc[4];
        float m3 = (sel & 1) ? bc[7]  : bc[6];
        float m4 = (sel & 1) ? bc[9]  : bc[8];
        float m5 = (sel & 1) ? bc[11] : bc[10];
        float m6 = (sel & 1) ? bc[13] : bc[12];
        float m7 = (sel & 1) ? 0.0f   : bc[14];
        float n0 = (sel & 2) ? m1 : m0;
        float n1 = (sel & 2) ? m3 : m2;
        float n2 = (sel & 2) ? m5 : m4;
        float n3 = (sel & 2) ? m7 : m6;
        float q0 = (sel & 4) ? n1 : n0;
        float q1 = (sel & 4) ? n3 : n2;
        float sv = (sel & 8) ? q1 : q0;

        const bool active = (lane < 16) && (sel < R);
        const bool is_neg = (sel >= len);
        float v = log_sigmoid(is_neg ? -sv : sv);
        float posc = (active && !is_neg) ? v : 0.0f;
        float negc = (active &&  is_neg) ? v : 0.0f;

        // sum lanes 0..15 (others are zero)
        posc += __shfl_xor(posc, 1, 64);
        posc += __shfl_xor(posc, 2, 64);
        posc += __shfl_xor(posc, 4, 64);
        posc += __shfl_xor(posc, 8, 64);
        negc += __shfl_xor(negc, 1, 64);
        negc += __shfl_xor(negc, 2, 64);
        negc += __shfl_xor(negc, 4, 64);
        negc += __shfl_xor(negc, 8, 64);

        res.x = -posc / (float)len;
        res.y = -negc * (1.0f / KNEG);
    }

    if (lane == 0) per_sample[b] = res;
}

// ---------------------------------------------------------------------------
// Kernel B: one thread per sample, reads 128 KB of float2 from L2.
// ---------------------------------------------------------------------------
__global__ __launch_bounds__(256) void reduce_kernel(
    const float2* __restrict__ per_sample,
    float*        __restrict__ out)
{
    const int tid = threadIdx.x;
    const int b   = blockIdx.x * 256 + tid;   // 64 blocks cover BATCH exactly

    const float2 pr = per_sample[b];
    float pos = pr.x;
    float neg = pr.y;

#pragma unroll
    for (int m = 32; m >= 1; m >>= 1) {
        pos += __shfl_xor(pos, m, 64);
        neg += __shfl_xor(neg, m, 64);
    }
    __shared__ float s_pos[4];
    __shared__ float s_neg[4];
    const int wave = tid >> 6;
    if ((tid & 63) == 0) { s_pos[wave] = pos; s_neg[wave] = neg; }
    __syncthreads();
    if (tid == 0) {
        float ps = s_pos[0] + s_pos[1] + s_pos[2] + s_pos[3];
        float ns = s_neg[0] + s_neg[1] + s_neg[2] + s_neg[3];
        atomicAdd(&out[0], ps * (1.0f / BATCH));
        atomicAdd(&out[1], ns * (1.0f / BATCH));
    }
}

extern "C" void kernel_launch(void* const* d_in, const int* in_sizes, int n_in,
                              void* d_out, int out_size, void* d_ws, size_t ws_size,
                              hipStream_t stream) {
    const int*   tgt     = (const int*)  d_in[0];
    const int*   ctx     = (const int*)  d_in[1];
    const int*   lens    = (const int*)  d_in[2];
    const int*   neg     = (const int*)  d_in[3];
    const float* in_emb  = (const float*)d_in[4];
    const float* out_emb = (const float*)d_in[5];
    float* out          = (float*)d_out;
    float2* per_sample  = (float2*)d_ws;      // BATCH * 8 B = 128 KiB scratch

    // one 64-lane wave per sample; 4 samples per 256-thread block
    score_loss_kernel<<<BATCH / 4, 256, 0, stream>>>(
        tgt, ctx, lens, neg, in_emb, out_emb, per_sample, out);

    reduce_kernel<<<BATCH / 256, 256, 0, stream>>>(per_sample, out);
}

// Round 3
// 126.902 us; speedup vs baseline: 1.9971x; 1.9971x over previous
//
#include <hip/hip_runtime.h>
#include <math.h>
#include <stdint.h>

#define VOCAB 100000
#define DIM   128
#define BATCH 16384
#define CMAX  10
#define KNEG  5

typedef float f32x4 __attribute__((ext_vector_type(4)));

// Numerically stable log(sigmoid(x)) = min(x,0) - log1p(exp(-|x|))
__device__ __forceinline__ float log_sigmoid(float x) {
    return fminf(x, 0.0f) - log1pf(expf(-fabsf(x)));
}

// DPP-based 32-lane sum: after 5 dependent VALU adds, lane 31 holds
// sum(lanes 0..31) and lane 63 holds sum(lanes 32..63).
#define DPP_ADD_STEP(v, ctrl)                                                  \
    v += __int_as_float(__builtin_amdgcn_update_dpp(                           \
        0, __float_as_int(v), (ctrl), 0xF, 0xF, false))

__device__ __forceinline__ float dpp_reduce32_to_lane31(float v) {
    DPP_ADD_STEP(v, 0x111);  // row_shr:1
    DPP_ADD_STEP(v, 0x112);  // row_shr:2
    DPP_ADD_STEP(v, 0x114);  // row_shr:4
    DPP_ADD_STEP(v, 0x118);  // row_shr:8
    DPP_ADD_STEP(v, 0x142);  // row_bcast:15
    return v;
}

// ---------------------------------------------------------------------------
// R1 structure (proven ~40 us): ONE WAVE per sample, half-wave h owns scores
// j = h*8 .. h*8+7 (j=15 dummy). 9 dwordx4 gathers per half-wave issued
// back-to-back, staged vmcnt waits, fused loss.
// R3 changes (both straight-line, no branches):
//  (a) index loads scalarized via readfirstlane -> s_load (SMEM/lgkmcnt):
//      fewer ops, fewer VGPRs, and vmcnt counts exactly our 9 asm gathers.
//  (b) masked ctx slots (j >= len) and the dummy slot redirect their word to
//      negw[0] via compile-time-indexed selects: the duplicate addresses hit
//      MSHR/L1 on the already-in-flight neg row -> repeat traffic -30%,
//      unique HBM fetch -10%. Garbage scores are finite and loss-masked.
// ---------------------------------------------------------------------------
__global__ __launch_bounds__(256) void score_loss_kernel(
    const int*   __restrict__ tgt,
    const int*   __restrict__ ctx,
    const int*   __restrict__ lens,
    const int*   __restrict__ neg,
    const float* __restrict__ in_emb,
    const float* __restrict__ out_emb,
    float2*      __restrict__ per_sample,  // ws: [BATCH]
    float*       __restrict__ out)
{
    const int tid  = threadIdx.x;
    const int lane = tid & 63;
    const int sub  = lane & 31;              // lane within half-wave
    const int half = lane >> 5;              // which 8-score group
    const int b    = (blockIdx.x * 256 + tid) >> 6;   // one wave per sample
    const int bu   = __builtin_amdgcn_readfirstlane(b);

    if (blockIdx.x == 0 && tid < 2) out[tid] = 0.0f;

    // ---- scalar index loads (uniform address -> s_load, lgkmcnt domain) ----
    const int len    = lens[bu];
    const int t_word = tgt[bu];
    int ctxw[CMAX];
#pragma unroll
    for (int c = 0; c < CMAX; ++c) ctxw[c] = ctx[bu * CMAX + c];
    int negw[KNEG];
#pragma unroll
    for (int k = 0; k < KNEG; ++k) negw[k] = neg[bu * KNEG + k];

    // ---- per-half word table, all indices compile-time (rule #20) ----
    int words[8];
#pragma unroll
    for (int jj = 0; jj < 8; ++jj) {
        // half 0 slot: j = jj (always a ctx slot); mask to negw[0] if j>=len
        const int w0 = (jj < len) ? ctxw[jj] : negw[0];
        // half 1 slot: j = 8+jj
        int w1;
        if (jj < 2)       w1 = ((8 + jj) < len) ? ctxw[8 + jj] : negw[0];
        else if (jj < 7)  w1 = negw[jj - 2];     // j = 10..14
        else              w1 = negw[0];          // j = 15 dummy
        words[jj] = half ? w1 : w0;
    }

    // Drain vmem (only the out[] zero-store can be outstanding here; index
    // loads are SMEM) so vmcnt counts exactly our 9 gathers.
    asm volatile("s_waitcnt vmcnt(0)" ::: "memory");

    // ---- issue all 9 row gathers back-to-back ----
    const uint32_t sub16 = (uint32_t)sub * 16u;
    f32x4 tv;
    {
        uint32_t off = (uint32_t)t_word * (DIM * 4u) + sub16;
        asm volatile("global_load_dwordx4 %0, %1, %2"
                     : "=v"(tv) : "v"(off), "s"(in_emb));
    }
    f32x4 rv[8];
#pragma unroll
    for (int jj = 0; jj < 8; ++jj) {
        uint32_t off = (uint32_t)words[jj] * (DIM * 4u) + sub16;
        asm volatile("global_load_dwordx4 %0, %1, %2"
                     : "=v"(rv[jj]) : "v"(off), "s"(out_emb));
    }

    // ---- staged waits: consume load jj once tv and rv[0..jj] have landed ----
    float p[8];
#pragma unroll
    for (int jj = 0; jj < 8; ++jj) {
        asm volatile("s_waitcnt vmcnt(%[cnt])"
                     : "+v"(rv[jj]), "+v"(tv)
                     : [cnt] "i"(7 - jj)
                     : "memory");
        float d = tv.x * rv[jj].x + tv.y * rv[jj].y +
                  tv.z * rv[jj].z + tv.w * rv[jj].w;
        p[jj] = dpp_reduce32_to_lane31(d);   // valid on lanes 31 / 63
    }

    // ---- fused loss: broadcast 8 half-scores, 8 lanes per half do the math ----
    float bc[8];
#pragma unroll
    for (int jj = 0; jj < 8; ++jj) bc[jj] = __shfl(p[jj], 31, 32);

    const int sel = sub & 7;
    float a0 = (sel & 1) ? bc[1] : bc[0];
    float a1 = (sel & 1) ? bc[3] : bc[2];
    float a2 = (sel & 1) ? bc[5] : bc[4];
    float a3 = (sel & 1) ? bc[7] : bc[6];
    float b0 = (sel & 2) ? a1 : a0;
    float b1 = (sel & 2) ? a3 : a2;
    float s  = (sel & 4) ? b1 : b0;

    const int  j        = half * 8 + sel;
    const bool neg_slot = (j >= CMAX) && (j < CMAX + KNEG);
    const bool active   = (sub < 8);

    float v    = log_sigmoid(neg_slot ? -s : s);
    // j<len implies j<=9 (len<=CMAX), so pos/neg never overlap; j=15 dummy and
    // masked ctx slots (their s is the harmless t . neg0 score) fail both.
    float posc = (active && j < len)  ? v : 0.0f;
    float negc = (active && neg_slot) ? v : 0.0f;

    posc += __shfl_xor(posc, 1, 64);
    posc += __shfl_xor(posc, 2, 64);
    posc += __shfl_xor(posc, 4, 64);
    posc += __shfl_xor(posc, 32, 64);
    negc += __shfl_xor(negc, 1, 64);
    negc += __shfl_xor(negc, 2, 64);
    negc += __shfl_xor(negc, 4, 64);
    negc += __shfl_xor(negc, 32, 64);

    if (lane == 0) {
        float2 r;
        if (len > 0) {
            r.x = -posc / (float)len;
            r.y = -negc * (1.0f / KNEG);
        } else {
            r.x = 0.0f;
            r.y = 0.0f;
        }
        per_sample[b] = r;
    }
}

// ---------------------------------------------------------------------------
// Kernel B: one thread per sample, reads 128 KB of float2 from L2.
// ---------------------------------------------------------------------------
__global__ __launch_bounds__(256) void reduce_kernel(
    const float2* __restrict__ per_sample,
    float*        __restrict__ out)
{
    const int tid = threadIdx.x;
    const int b   = blockIdx.x * 256 + tid;   // 64 blocks cover BATCH exactly

    const float2 pr = per_sample[b];
    float pos = pr.x;
    float neg = pr.y;

#pragma unroll
    for (int m = 32; m >= 1; m >>= 1) {
        pos += __shfl_xor(pos, m, 64);
        neg += __shfl_xor(neg, m, 64);
    }
    __shared__ float s_pos[4];
    __shared__ float s_neg[4];
    const int wave = tid >> 6;
    if ((tid & 63) == 0) { s_pos[wave] = pos; s_neg[wave] = neg; }
    __syncthreads();
    if (tid == 0) {
        float ps = s_pos[0] + s_pos[1] + s_pos[2] + s_pos[3];
        float ns = s_neg[0] + s_neg[1] + s_neg[2] + s_neg[3];
        atomicAdd(&out[0], ps * (1.0f / BATCH));
        atomicAdd(&out[1], ns * (1.0f / BATCH));
    }
}

extern "C" void kernel_launch(void* const* d_in, const int* in_sizes, int n_in,
                              void* d_out, int out_size, void* d_ws, size_t ws_size,
                              hipStream_t stream) {
    const int*   tgt     = (const int*)  d_in[0];
    const int*   ctx     = (const int*)  d_in[1];
    const int*   lens    = (const int*)  d_in[2];
    const int*   neg     = (const int*)  d_in[3];
    const float* in_emb  = (const float*)d_in[4];
    const float* out_emb = (const float*)d_in[5];
    float* out          = (float*)d_out;
    float2* per_sample  = (float2*)d_ws;      // BATCH * 8 B = 128 KiB scratch

    // one 64-lane wave per sample; 4 samples per 256-thread block
    score_loss_kernel<<<BATCH / 4, 256, 0, stream>>>(
        tgt, ctx, lens, neg, in_emb, out_emb, per_sample, out);

    reduce_kernel<<<BATCH / 256, 256, 0, stream>>>(per_sample, out);
}